// Round 4
// baseline (931.365 us; speedup 1.0000x reference)
//
#include <hip/hip_runtime.h>
#include <math.h>

#define DIM 256
#define NCROPS 10
#define EPSF 1e-8f

#define BM 128
#define BK 32
#define LPAD 4
#define LW (BM + LPAD)   // 132 floats per LDS row; %4==0 keeps b128 16B-aligned

// ---------------------------------------------------------------------------
// Kernel 1: row-wise L2 normalize. One block (256 threads) per row.
// ---------------------------------------------------------------------------
__global__ void normalize_k(const float* __restrict__ X, float* __restrict__ Xn) {
  const int row = blockIdx.x;
  const int t = threadIdx.x;
  const float v = X[(size_t)row * DIM + t];
  float sq = v * v;
#pragma unroll
  for (int off = 32; off > 0; off >>= 1) sq += __shfl_down(sq, off, 64);
  __shared__ float parts[4];
  __shared__ float scale;
  if ((t & 63) == 0) parts[t >> 6] = sq;
  __syncthreads();
  if (t == 0) {
    const float total = parts[0] + parts[1] + parts[2] + parts[3];
    scale = 1.0f / fmaxf(sqrtf(total), EPSF);
  }
  __syncthreads();
  Xn[(size_t)row * DIM + t] = v * scale;
}

// ---------------------------------------------------------------------------
// Kernel 2: fused X @ X^T + per-row argmax (diagonal excluded).
// 128x128 tile per block, 256 threads, 8x8 micro-tile per thread, BK=32.
// Per-row running max held as packed u64 key: (sortable_f32 << 32) | ~col,
// so atomicMax yields max value with lowest col index on ties (jnp.argmax).
// ---------------------------------------------------------------------------
__device__ __forceinline__ unsigned long long shfl_xor_u64(unsigned long long x, int mask) {
  unsigned lo = (unsigned)x;
  unsigned hi = (unsigned)(x >> 32);
  lo = (unsigned)__shfl_xor((int)lo, mask, 64);
  hi = (unsigned)__shfl_xor((int)hi, mask, 64);
  return ((unsigned long long)hi << 32) | (unsigned long long)lo;
}

__global__ __launch_bounds__(256) void gemm_argmax_k(
    const float* __restrict__ Xn, unsigned long long* __restrict__ keys) {
  __shared__ float As[BK][LW];
  __shared__ float Bs[BK][LW];

  const int tid = threadIdx.x;
  const int tx = tid & 15;   // 0..15
  const int ty = tid >> 4;   // 0..15
  const int rowBase = blockIdx.y * BM;
  const int colBase = blockIdx.x * BM;

  float acc[8][8];
#pragma unroll
  for (int a = 0; a < 8; ++a)
#pragma unroll
    for (int b = 0; b < 8; ++b) acc[a][b] = 0.f;

  const int kg = tid & 7;    // k-group within tile (4 floats each)
  const int r0 = tid >> 3;   // 0..31

  for (int kt = 0; kt < DIM / BK; ++kt) {
    const int k0 = kt * BK;
    // stage: global (float4 along k) -> LDS transposed (k-major)
#pragma unroll
    for (int i = 0; i < 4; ++i) {
      const int r = r0 + 32 * i;
      const float4 av = *(const float4*)(Xn + (size_t)(rowBase + r) * DIM + k0 + 4 * kg);
      const float4 bv = *(const float4*)(Xn + (size_t)(colBase + r) * DIM + k0 + 4 * kg);
      As[4 * kg + 0][r] = av.x; As[4 * kg + 1][r] = av.y;
      As[4 * kg + 2][r] = av.z; As[4 * kg + 3][r] = av.w;
      Bs[4 * kg + 0][r] = bv.x; Bs[4 * kg + 1][r] = bv.y;
      Bs[4 * kg + 2][r] = bv.z; Bs[4 * kg + 3][r] = bv.w;
    }
    __syncthreads();

#pragma unroll
    for (int k = 0; k < BK; ++k) {
      const float4 a0 = *(const float4*)&As[k][ty * 8];
      const float4 a1 = *(const float4*)&As[k][ty * 8 + 4];
      const float4 b0 = *(const float4*)&Bs[k][tx * 4];
      const float4 b1 = *(const float4*)&Bs[k][tx * 4 + 64];
      const float av[8] = {a0.x, a0.y, a0.z, a0.w, a1.x, a1.y, a1.z, a1.w};
      const float bv[8] = {b0.x, b0.y, b0.z, b0.w, b1.x, b1.y, b1.z, b1.w};
#pragma unroll
      for (int a = 0; a < 8; ++a)
#pragma unroll
        for (int b = 0; b < 8; ++b)
          acc[a][b] = fmaf(av[a], bv[b], acc[a][b]);
    }
    __syncthreads();
  }

  // epilogue: per-row argmax over this 128-col tile, then global atomicMax
#pragma unroll
  for (int a = 0; a < 8; ++a) {
    const int i = rowBase + ty * 8 + a;
    unsigned long long best = 0ull;
#pragma unroll
    for (int c = 0; c < 8; ++c) {
      const int col = colBase + 4 * tx + (c & 3) + 64 * (c >> 2);
      const float v = (col == i) ? -2.0f : acc[a][c];
      const unsigned u = __float_as_uint(v);
      const unsigned s = (u & 0x80000000u) ? ~u : (u | 0x80000000u);
      const unsigned long long key =
          ((unsigned long long)s << 32) |
          (unsigned long long)(0xFFFFFFFFu - (unsigned)col);
      best = key > best ? key : best;
    }
    // reduce across the 16 tx lanes (same wave: lane = ty*16+tx, ty fixed bits)
#pragma unroll
    for (int off = 1; off < 16; off <<= 1) {
      const unsigned long long o = shfl_xor_u64(best, off);
      best = o > best ? o : best;
    }
    if (tx == 0) atomicMax(keys + i, best);
  }
}

// ---------------------------------------------------------------------------
// Kernel 3: per-row distance to NN (exactly as reference: x - x[I] + eps,
// elementwise, then sqrt, log), accumulate -log/n into out.
// ---------------------------------------------------------------------------
__global__ void finish_k(const float* __restrict__ Xn,
                         const unsigned long long* __restrict__ keys,
                         float* __restrict__ out, int n) {
  const int i = blockIdx.x;
  const int t = threadIdx.x;
  const unsigned long long key = keys[i];
  const int I = (int)(0xFFFFFFFFu - (unsigned)(key & 0xFFFFFFFFull));
  const float d = Xn[(size_t)i * DIM + t] - Xn[(size_t)I * DIM + t] + EPSF;
  float v = d * d;
#pragma unroll
  for (int off = 32; off > 0; off >>= 1) v += __shfl_down(v, off, 64);
  __shared__ float parts[4];
  if ((t & 63) == 0) parts[t >> 6] = v;
  __syncthreads();
  if (t == 0) {
    const float total = parts[0] + parts[1] + parts[2] + parts[3];
    const float dist = sqrtf(total);
    atomicAdd(out, -logf(dist + EPSF) / (float)n);
  }
}

// ---------------------------------------------------------------------------
extern "C" void kernel_launch(void* const* d_in, const int* in_sizes, int n_in,
                              void* d_out, int out_size, void* d_ws, size_t ws_size,
                              hipStream_t stream) {
  const float* X = (const float*)d_in[0];
  float* out = (float*)d_out;

  const int n = in_sizes[0] / (DIM * NCROPS);  // 8192

  float* Xn = (float*)d_ws;
  unsigned long long* keys =
      (unsigned long long*)((char*)d_ws + (size_t)n * DIM * sizeof(float));

  hipMemsetAsync(keys, 0, (size_t)n * sizeof(unsigned long long), stream);
  hipMemsetAsync(out, 0, sizeof(float), stream);

  normalize_k<<<n, 256, 0, stream>>>(X, Xn);

  dim3 grid(n / BM, n / BM);
  gemm_argmax_k<<<grid, 256, 0, stream>>>(Xn, keys);

  finish_k<<<n, 256, 0, stream>>>(Xn, keys, out, n);
}

// Round 6
// 314.456 us; speedup vs baseline: 2.9618x; 2.9618x over previous
//
#include <hip/hip_runtime.h>
#include <hip/hip_bf16.h>
#include <math.h>

#define DIM 256
#define NCROPS 10
#define EPSF 1e-8f

typedef short bf16x8 __attribute__((ext_vector_type(8)));
typedef float f32x4 __attribute__((ext_vector_type(4)));

// ---------------------------------------------------------------------------
// Kernel 1: row-wise L2 normalize. One block (256 threads) per row.
// Writes f32 Xn (for exact distance recompute) and bf16 Xb (for MFMA Gram).
// ---------------------------------------------------------------------------
__global__ void normalize_k(const float* __restrict__ X, float* __restrict__ Xn,
                            __hip_bfloat16* __restrict__ Xb) {
  const int row = blockIdx.x;
  const int t = threadIdx.x;
  const float v = X[(size_t)row * DIM + t];
  float sq = v * v;
#pragma unroll
  for (int off = 32; off > 0; off >>= 1) sq += __shfl_down(sq, off, 64);
  __shared__ float parts[4];
  __shared__ float scale;
  if ((t & 63) == 0) parts[t >> 6] = sq;
  __syncthreads();
  if (t == 0) {
    const float total = parts[0] + parts[1] + parts[2] + parts[3];
    scale = 1.0f / fmaxf(sqrtf(total), EPSF);
  }
  __syncthreads();
  const float xn = v * scale;
  Xn[(size_t)row * DIM + t] = xn;
  Xb[(size_t)row * DIM + t] = __float2bfloat16(xn);
}

// ---------------------------------------------------------------------------
// Kernel 2: bf16 MFMA Gram (Xb @ Xb^T) fused with per-row argmax (diag excl).
// 128x128 tile per block, 256 threads = 4 waves, each wave owns 64x64 out.
// K=256 staged in 4 chunks of 64 (LDS 2 x 16 KB, XOR-swizzled rows).
// mfma_f32_16x16x32_bf16; C/D layout: col=lane&15, row=(lane>>4)*4+reg.
// Per-row running max as packed u64 key (sortable_f32<<32)|~col -> atomicMax
// gives max value with lowest col on ties (matches jnp.argmax).
// ---------------------------------------------------------------------------
__device__ __forceinline__ unsigned long long shfl_xor_u64(unsigned long long x, int mask) {
  unsigned lo = (unsigned)x;
  unsigned hi = (unsigned)(x >> 32);
  lo = (unsigned)__shfl_xor((int)lo, mask, 64);
  hi = (unsigned)__shfl_xor((int)hi, mask, 64);
  return ((unsigned long long)hi << 32) | (unsigned long long)lo;
}

__device__ __forceinline__ unsigned long long umax64(unsigned long long a, unsigned long long b) {
  return a > b ? a : b;
}

#define BKC 64  // K-chunk

__global__ __launch_bounds__(256) void mfma_argmax_k(
    const __hip_bfloat16* __restrict__ Xb, unsigned long long* __restrict__ keys) {
  // 128 rows x 64 k of bf16 = 16 KB per panel; row stride 128 B, XOR-swizzled.
  __shared__ char As[16384];
  __shared__ char Bs[16384];

  const int tid = threadIdx.x;
  const int lane = tid & 63;
  const int wave = tid >> 6;
  const int wr = (wave >> 1) * 64;  // wave's row offset in block tile
  const int wc = (wave & 1) * 64;   // wave's col offset
  const int rowBase = blockIdx.y * 128;
  const int colBase = blockIdx.x * 128;

  f32x4 acc[4][4];
#pragma unroll
  for (int m = 0; m < 4; ++m)
#pragma unroll
    for (int n = 0; n < 4; ++n) acc[m][n] = (f32x4){0.f, 0.f, 0.f, 0.f};

  const char* gA = (const char*)Xb + (size_t)rowBase * DIM * 2;
  const char* gB = (const char*)Xb + (size_t)colBase * DIM * 2;

  for (int kt = 0; kt < DIM / BKC; ++kt) {
    // stage: 1024 16B-chunks per panel, 4 per thread. row=c>>3, kchunk=c&7.
    __syncthreads();
#pragma unroll
    for (int i = 0; i < 4; ++i) {
      const int c = tid + 256 * i;
      const int row = c >> 3;
      const int kc = c & 7;
      int byte = row * 128 + kc * 16;
      byte ^= (row & 7) << 4;
      const size_t goff = ((size_t)row * DIM + kt * BKC + kc * 8) * 2;
      *(float4*)(As + byte) = *(const float4*)(gA + goff);
      *(float4*)(Bs + byte) = *(const float4*)(gB + goff);
    }
    __syncthreads();

#pragma unroll
    for (int ks = 0; ks < 2; ++ks) {
      const int kbyte = ks * 64 + ((lane >> 4) << 4);  // 32 k per mfma step
      bf16x8 a[4], b[4];
#pragma unroll
      for (int m = 0; m < 4; ++m) {
        const int r = wr + m * 16 + (lane & 15);
        a[m] = *(const bf16x8*)(As + ((r * 128 + kbyte) ^ ((r & 7) << 4)));
      }
#pragma unroll
      for (int n = 0; n < 4; ++n) {
        const int r = wc + n * 16 + (lane & 15);
        b[n] = *(const bf16x8*)(Bs + ((r * 128 + kbyte) ^ ((r & 7) << 4)));
      }
#pragma unroll
      for (int m = 0; m < 4; ++m)
#pragma unroll
        for (int n = 0; n < 4; ++n)
          acc[m][n] = __builtin_amdgcn_mfma_f32_16x16x32_bf16(a[m], b[n], acc[m][n], 0, 0, 0);
    }
  }

  // epilogue: per-row argmax over this wave's 64 cols, then global atomicMax.
  const int rfb = (lane >> 4) * 4;  // row base within 16x16 fragment
#pragma unroll
  for (int m = 0; m < 4; ++m) {
#pragma unroll
    for (int r = 0; r < 4; ++r) {
      const int grow = rowBase + wr + m * 16 + rfb + r;
      unsigned long long best = 0ull;
#pragma unroll
      for (int n = 0; n < 4; ++n) {
        const int gcol = colBase + wc + n * 16 + (lane & 15);
        float v = acc[m][n][r];
        if (gcol == grow) v = -2.0f;
        const unsigned u = __float_as_uint(v);
        const unsigned s = (u & 0x80000000u) ? ~u : (u | 0x80000000u);
        const unsigned long long key =
            ((unsigned long long)s << 32) |
            (unsigned long long)(0xFFFFFFFFu - (unsigned)gcol);
        best = umax64(best, key);
      }
      // reduce over the 16 lanes of this quarter-wave (bits 0..3 of lane)
#pragma unroll
      for (int off = 1; off < 16; off <<= 1) best = umax64(best, shfl_xor_u64(best, off));
      if ((lane & 15) == 0) atomicMax(keys + grow, best);
    }
  }
}

// ---------------------------------------------------------------------------
// Kernel 3: per-row NN distance (exact reference arithmetic on f32 Xn:
// x - x[I] + eps elementwise, sqrt, log), accumulate -log/n into out.
// ---------------------------------------------------------------------------
__global__ void finish_k(const float* __restrict__ Xn,
                         const unsigned long long* __restrict__ keys,
                         float* __restrict__ out, int n) {
  const int i = blockIdx.x;
  const int t = threadIdx.x;
  const unsigned long long key = keys[i];
  const int I = (int)(0xFFFFFFFFu - (unsigned)(key & 0xFFFFFFFFull));
  const float d = Xn[(size_t)i * DIM + t] - Xn[(size_t)I * DIM + t] + EPSF;
  float v = d * d;
#pragma unroll
  for (int off = 32; off > 0; off >>= 1) v += __shfl_down(v, off, 64);
  __shared__ float parts[4];
  if ((t & 63) == 0) parts[t >> 6] = v;
  __syncthreads();
  if (t == 0) {
    const float total = parts[0] + parts[1] + parts[2] + parts[3];
    const float dist = sqrtf(total);
    atomicAdd(out, -logf(dist + EPSF) / (float)n);
  }
}

// ---------------------------------------------------------------------------
extern "C" void kernel_launch(void* const* d_in, const int* in_sizes, int n_in,
                              void* d_out, int out_size, void* d_ws, size_t ws_size,
                              hipStream_t stream) {
  const float* X = (const float*)d_in[0];
  float* out = (float*)d_out;

  const int n = in_sizes[0] / (DIM * NCROPS);  // 8192

  float* Xn = (float*)d_ws;                                            // 8 MB
  __hip_bfloat16* Xb =
      (__hip_bfloat16*)((char*)d_ws + (size_t)n * DIM * sizeof(float)); // 4 MB
  unsigned long long* keys =
      (unsigned long long*)((char*)d_ws + (size_t)n * DIM * 6);         // 64 KB

  hipMemsetAsync(keys, 0, (size_t)n * sizeof(unsigned long long), stream);
  hipMemsetAsync(out, 0, sizeof(float), stream);

  normalize_k<<<n, 256, 0, stream>>>(X, Xn, Xb);

  dim3 grid(n / 128, n / 128);
  mfma_argmax_k<<<grid, 256, 0, stream>>>(Xb, keys);

  finish_k<<<n, 256, 0, stream>>>(Xn, keys, out, n);
}

// Round 10
// 209.666 us; speedup vs baseline: 4.4421x; 1.4998x over previous
//
#include <hip/hip_runtime.h>
#include <math.h>

#define DIM 256
#define NCROPS 10
#define EPSF 1e-8f

typedef short bf16x8 __attribute__((ext_vector_type(8)));
typedef float f32x4 __attribute__((ext_vector_type(4)));

// manual RNE f32->bf16 (values here are normal, no NaN/Inf)
__device__ __forceinline__ unsigned short f32_to_bf16(float x) {
  unsigned u = __float_as_uint(x);
  u += 0x7FFFu + ((u >> 16) & 1u);
  return (unsigned short)(u >> 16);
}

// ---------------------------------------------------------------------------
// Kernel 1: row-wise L2 normalize. 4 waves/block, 8 rows per wave.
// float4 loads (16 B/lane); butterfly reduce; writes f32 Xn (for exact
// distance recompute) and bf16 Xb (for MFMA Gram).
// ---------------------------------------------------------------------------
__global__ __launch_bounds__(256) void normalize_k(const float* __restrict__ X,
                                                   float* __restrict__ Xn,
                                                   unsigned short* __restrict__ Xb) {
  const int lane = threadIdx.x & 63;
  const int wave = threadIdx.x >> 6;
  const int w = blockIdx.x * 4 + wave;
#pragma unroll
  for (int rr = 0; rr < 8; ++rr) {
    const int row = w * 8 + rr;
    const float4 v = *(const float4*)(X + (size_t)row * DIM + lane * 4);
    float sq = v.x * v.x + v.y * v.y + v.z * v.z + v.w * v.w;
#pragma unroll
    for (int off = 32; off > 0; off >>= 1) sq += __shfl_xor(sq, off, 64);
    const float scale = 1.0f / fmaxf(sqrtf(sq), EPSF);
    float4 o;
    o.x = v.x * scale; o.y = v.y * scale; o.z = v.z * scale; o.w = v.w * scale;
    *(float4*)(Xn + (size_t)row * DIM + lane * 4) = o;
    ushort4 ob;
    ob.x = f32_to_bf16(o.x); ob.y = f32_to_bf16(o.y);
    ob.z = f32_to_bf16(o.z); ob.w = f32_to_bf16(o.w);
    *(ushort4*)(Xb + (size_t)row * DIM + lane * 4) = ob;
  }
}

// ---------------------------------------------------------------------------
// Kernel 2: bf16 MFMA Gram (Xb @ Xb^T) fused with per-row argmax (diag excl),
// SYMMETRY-HALVED: only upper-triangle tile-blocks (bx >= by) compute; each
// block feeds keys twice from the same acc:
//   row-epilogue: max over cols  -> keys[row], index = col  (verified r6)
//   col-epilogue: max over rows  -> keys[col], index = row  (dots symmetric)
// Diagonal blocks double-feed bitwise-identical keys (atomicMax-idempotent).
// 128x128 tile, 4 waves each owning 64x64; K staged in 4 chunks of 64
// (LDS 2 x 16 KB, XOR-swizzled rows). mfma_f32_16x16x32_bf16;
// C/D layout: col=lane&15, row=(lane>>4)*4+reg.
// Key = (sortable_f32<<32) | ~index -> atomicMax = max val, lowest index tie.
// ---------------------------------------------------------------------------
__device__ __forceinline__ unsigned long long shfl_xor_u64(unsigned long long x, int mask) {
  unsigned lo = (unsigned)x;
  unsigned hi = (unsigned)(x >> 32);
  lo = (unsigned)__shfl_xor((int)lo, mask, 64);
  hi = (unsigned)__shfl_xor((int)hi, mask, 64);
  return ((unsigned long long)hi << 32) | (unsigned long long)lo;
}

__device__ __forceinline__ unsigned long long umax64(unsigned long long a, unsigned long long b) {
  return a > b ? a : b;
}

__device__ __forceinline__ unsigned long long pack_key(float v, int idx) {
  const unsigned u = __float_as_uint(v);
  const unsigned s = (u & 0x80000000u) ? ~u : (u | 0x80000000u);
  return ((unsigned long long)s << 32) |
         (unsigned long long)(0xFFFFFFFFu - (unsigned)idx);
}

#define BKC 64  // K-chunk

__global__ __launch_bounds__(256) void mfma_argmax_k(
    const unsigned short* __restrict__ Xb, unsigned long long* __restrict__ keys) {
  if (blockIdx.x < blockIdx.y) return;  // lower-triangle blocks: skip

  // 128 rows x 64 k of bf16 = 16 KB per panel; row stride 128 B, XOR-swizzled.
  __shared__ char As[16384];
  __shared__ char Bs[16384];

  const int tid = threadIdx.x;
  const int lane = tid & 63;
  const int wave = tid >> 6;
  const int wr = (wave >> 1) * 64;  // wave's row offset in block tile
  const int wc = (wave & 1) * 64;   // wave's col offset
  const int rowBase = blockIdx.y * 128;
  const int colBase = blockIdx.x * 128;

  f32x4 acc[4][4];
#pragma unroll
  for (int m = 0; m < 4; ++m)
#pragma unroll
    for (int n = 0; n < 4; ++n) acc[m][n] = (f32x4){0.f, 0.f, 0.f, 0.f};

  const char* gA = (const char*)Xb + (size_t)rowBase * DIM * 2;
  const char* gB = (const char*)Xb + (size_t)colBase * DIM * 2;

  for (int kt = 0; kt < DIM / BKC; ++kt) {
    // stage: 1024 16B-chunks per panel, 4 per thread. row=c>>3, kchunk=c&7.
    __syncthreads();
#pragma unroll
    for (int i = 0; i < 4; ++i) {
      const int c = tid + 256 * i;
      const int row = c >> 3;
      const int kc = c & 7;
      int byte = row * 128 + kc * 16;
      byte ^= (row & 7) << 4;
      const size_t goff = ((size_t)row * DIM + kt * BKC + kc * 8) * 2;
      *(float4*)(As + byte) = *(const float4*)(gA + goff);
      *(float4*)(Bs + byte) = *(const float4*)(gB + goff);
    }
    __syncthreads();

#pragma unroll
    for (int ks = 0; ks < 2; ++ks) {
      const int kbyte = ks * 64 + ((lane >> 4) << 4);  // 32 k per mfma step
      bf16x8 a[4], b[4];
#pragma unroll
      for (int m = 0; m < 4; ++m) {
        const int r = wr + m * 16 + (lane & 15);
        a[m] = *(const bf16x8*)(As + ((r * 128 + kbyte) ^ ((r & 7) << 4)));
      }
#pragma unroll
      for (int n = 0; n < 4; ++n) {
        const int r = wc + n * 16 + (lane & 15);
        b[n] = *(const bf16x8*)(Bs + ((r * 128 + kbyte) ^ ((r & 7) << 4)));
      }
#pragma unroll
      for (int m = 0; m < 4; ++m)
#pragma unroll
        for (int n = 0; n < 4; ++n)
          acc[m][n] = __builtin_amdgcn_mfma_f32_16x16x32_bf16(a[m], b[n], acc[m][n], 0, 0, 0);
    }
  }

  const int rfb = (lane >> 4) * 4;  // row base within 16x16 fragment

  // ---- row-epilogue: per-row argmax over this wave's 64 cols -> keys[row]
#pragma unroll
  for (int m = 0; m < 4; ++m) {
#pragma unroll
    for (int r = 0; r < 4; ++r) {
      const int grow = rowBase + wr + m * 16 + rfb + r;
      unsigned long long best = 0ull;
#pragma unroll
      for (int n = 0; n < 4; ++n) {
        const int gcol = colBase + wc + n * 16 + (lane & 15);
        float v = acc[m][n][r];
        if (gcol == grow) v = -2.0f;
        best = umax64(best, pack_key(v, gcol));
      }
      // reduce over the 16 lanes of this quarter-group (lane bits 0..3)
#pragma unroll
      for (int off = 1; off < 16; off <<= 1) best = umax64(best, shfl_xor_u64(best, off));
      if ((lane & 15) == 0) atomicMax(keys + grow, best);
    }
  }

  // ---- col-epilogue: per-col argmax over this wave's 64 rows -> keys[col]
  // (dots[i][j] == dots[j][i]; candidate index is the ROW)
#pragma unroll
  for (int n = 0; n < 4; ++n) {
    const int gcol = colBase + wc + n * 16 + (lane & 15);
    unsigned long long best = 0ull;
#pragma unroll
    for (int m = 0; m < 4; ++m) {
#pragma unroll
      for (int r = 0; r < 4; ++r) {
        const int grow = rowBase + wr + m * 16 + rfb + r;
        float v = acc[m][n][r];
        if (gcol == grow) v = -2.0f;
        best = umax64(best, pack_key(v, grow));
      }
    }
    // combine the 4 row-groups (lane bits 4..5); all lanes get their col's max
    best = umax64(best, shfl_xor_u64(best, 16));
    best = umax64(best, shfl_xor_u64(best, 32));
    if (lane < 16) atomicMax(keys + gcol, best);
  }
}

// ---------------------------------------------------------------------------
// Kernel 3: per-row NN distance (exact reference arithmetic on f32 Xn:
// x - x[I] + eps elementwise, sqrt, log). 4 waves/block, 8 rows per wave;
// float4 loads; lane0 accumulates -log across rows; ONE atomicAdd per block.
// ---------------------------------------------------------------------------
__global__ __launch_bounds__(256) void finish_k(const float* __restrict__ Xn,
                                                const unsigned long long* __restrict__ keys,
                                                float* __restrict__ out, int n) {
  const int lane = threadIdx.x & 63;
  const int wave = threadIdx.x >> 6;
  const int w = blockIdx.x * 4 + wave;
  float acc = 0.f;
#pragma unroll
  for (int rr = 0; rr < 8; ++rr) {
    const int row = w * 8 + rr;
    const unsigned long long key = keys[row];
    const int I = (int)(0xFFFFFFFFu - (unsigned)(key & 0xFFFFFFFFull));
    const float4 a = *(const float4*)(Xn + (size_t)row * DIM + lane * 4);
    const float4 b = *(const float4*)(Xn + (size_t)I * DIM + lane * 4);
    const float dx = a.x - b.x + EPSF;
    const float dy = a.y - b.y + EPSF;
    const float dz = a.z - b.z + EPSF;
    const float dw = a.w - b.w + EPSF;
    float s = dx * dx + dy * dy + dz * dz + dw * dw;
#pragma unroll
    for (int off = 32; off > 0; off >>= 1) s += __shfl_xor(s, off, 64);
    if (lane == 0) acc += -logf(sqrtf(s) + EPSF);
  }
  __shared__ float parts[4];
  if (lane == 0) parts[wave] = acc;
  __syncthreads();
  if (threadIdx.x == 0) {
    atomicAdd(out, (parts[0] + parts[1] + parts[2] + parts[3]) / (float)n);
  }
}

// ---------------------------------------------------------------------------
extern "C" void kernel_launch(void* const* d_in, const int* in_sizes, int n_in,
                              void* d_out, int out_size, void* d_ws, size_t ws_size,
                              hipStream_t stream) {
  const float* X = (const float*)d_in[0];
  float* out = (float*)d_out;

  const int n = in_sizes[0] / (DIM * NCROPS);  // 8192

  float* Xn = (float*)d_ws;                                             // 8 MB
  unsigned short* Xb =
      (unsigned short*)((char*)d_ws + (size_t)n * DIM * sizeof(float));  // 4 MB
  unsigned long long* keys =
      (unsigned long long*)((char*)d_ws + (size_t)n * DIM * 6);          // 64 KB

  hipMemsetAsync(keys, 0, (size_t)n * sizeof(unsigned long long), stream);
  hipMemsetAsync(out, 0, sizeof(float), stream);

  const int rows_per_block = 32;  // 4 waves x 8 rows
  normalize_k<<<n / rows_per_block, 256, 0, stream>>>(X, Xn, Xb);

  dim3 grid(n / 128, n / 128);  // upper-triangle blocks compute; rest early-exit
  mfma_argmax_k<<<grid, 256, 0, stream>>>(Xb, keys);

  finish_k<<<n / rows_per_block, 256, 0, stream>>>(Xn, keys, out, n);
}